// Round 14
// baseline (311.063 us; speedup 1.0000x reference)
//
#include <hip/hip_runtime.h>

// ConvAttention forward, MI355X. fp32 I/O, bf16 intermediates, MFMA GEMMs.
// Round-11 proven GEMM (128xTN, BK=32, pitch 40, 4 waves) + dispatch fusion:
//   prologue = LN1 || cvt_weights || zero(d_out)
//   attn_all = patch (16 dual-query waves/block) || cls (48 blocks, 16-way PV)
//   midk     = LN2 || zero(tokf)
// Split-K (pool=4, fc2=4) + fp32 atomicAdd.
// ws (u16 units): h1 [0, 3151872) ; qkvb [3151872, 12607488) ;
//   wb [12607488, 15704064)  (bf16 weights: qkv|proj|pool|fc1|fc2)
//   att = q-cols of qkvb (lda 1152). After proj, qkvb region reused:
//   tokf (fp32) at qkvb+0 ; h3 at qkvb+1572864 ; mlp1 at qkvb+2362368.
// NOTE: tokf zeroing rides midk, stream-ordered AFTER proj (qkvb alias).

typedef unsigned short u16;
typedef unsigned int u32;
typedef short s16x8 __attribute__((ext_vector_type(8)));
typedef float f32x4 __attribute__((ext_vector_type(4)));

__device__ __forceinline__ float b2f(u16 u) {
    return __uint_as_float(((u32)u) << 16);
}
__device__ __forceinline__ u16 f2b(float f) {
    u32 u = __float_as_uint(f);
    return (u16)((u + 0x7FFFu + ((u >> 16) & 1u)) >> 16);  // RTNE
}
__device__ __forceinline__ float wave_sum(float v) {
#pragma unroll
    for (int o = 32; o > 0; o >>= 1) v += __shfl_xor(v, o, 64);
    return v;
}
__device__ __forceinline__ float wave_max(float v) {
#pragma unroll
    for (int o = 32; o > 0; o >>= 1) v = fmaxf(v, __shfl_xor(v, o, 64));
    return v;
}
__device__ __forceinline__ float half_sum(float v) {
#pragma unroll
    for (int o = 16; o > 0; o >>= 1) v += __shfl_xor(v, o, 64);
    return v;
}
__device__ __forceinline__ float half_max(float v) {
#pragma unroll
    for (int o = 16; o > 0; o >>= 1) v = fmaxf(v, __shfl_xor(v, o, 64));
    return v;
}
__device__ __forceinline__ float dot8(const float* qsh, int d0, uint4 u) {
    return qsh[d0 + 0] * b2f((u16)(u.x)) + qsh[d0 + 1] * b2f((u16)(u.x >> 16)) +
           qsh[d0 + 2] * b2f((u16)(u.y)) + qsh[d0 + 3] * b2f((u16)(u.y >> 16)) +
           qsh[d0 + 4] * b2f((u16)(u.z)) + qsh[d0 + 5] * b2f((u16)(u.z >> 16)) +
           qsh[d0 + 6] * b2f((u16)(u.w)) + qsh[d0 + 7] * b2f((u16)(u.w >> 16));
}

#define CCH 384
#define SCALE 0.40824829046386302f  // H^-0.5 = 6^-0.5
#define NEG_BIG (-1e30f)

// weight segment offsets in wb (u16 units)
#define W_QKV 0
#define W_PROJ 442368
#define W_POOL 589824
#define W_FC1 1916928
#define W_FC2 2506752
#define W_TOTAL 3096576

// ---------------- LN row helpers (per-wave, no block barriers) ---------------
__device__ __forceinline__ void ln_from_f32(const float* in, const float* w,
                                            const float* bb, u16* out,
                                            int lane) {
    float v[6];
    float s = 0.f, ss = 0.f;
#pragma unroll
    for (int i = 0; i < 6; i++) {
        v[i] = in[lane + 64 * i];
        s += v[i];
        ss += v[i] * v[i];
    }
    s = wave_sum(s);
    ss = wave_sum(ss);
    float mu = s * (1.f / 384.f);
    float var = ss * (1.f / 384.f) - mu * mu;
    float inv = rsqrtf(var + 1e-5f);
#pragma unroll
    for (int i = 0; i < 6; i++) {
        int c = lane + 64 * i;
        out[c] = f2b((v[i] - mu) * inv * w[c] + bb[c]);
    }
}
__device__ __forceinline__ void ln_from_b16(const u16* in, const float* w,
                                            const float* bb, u16* out,
                                            int lane) {
    float v[6];
    float s = 0.f, ss = 0.f;
#pragma unroll
    for (int i = 0; i < 6; i++) {
        v[i] = b2f(in[lane + 64 * i]);
        s += v[i];
        ss += v[i] * v[i];
    }
    s = wave_sum(s);
    ss = wave_sum(ss);
    float mu = s * (1.f / 384.f);
    float var = ss * (1.f / 384.f) - mu * mu;
    float inv = rsqrtf(var + 1e-5f);
#pragma unroll
    for (int i = 0; i < 6; i++) {
        int c = lane + 64 * i;
        out[c] = f2b((v[i] - mu) * inv * w[c] + bb[c]);
    }
}

// ---------------- prologue: LN1 || cvt_weights || zero(d_out) ----------------
#define PRO_LN 2052
#define PRO_CVT 1512
#define PRO_ZERO 771
__global__ __launch_bounds__(256) void prologue(
    const float* __restrict__ x, const float* __restrict__ n1w,
    const float* __restrict__ n1b, u16* __restrict__ h1,
    const float* __restrict__ qkv_w, const float* __restrict__ proj_w,
    const float* __restrict__ pool_w, const float* __restrict__ fc1_w,
    const float* __restrict__ fc2_w, u16* __restrict__ wb,
    float* __restrict__ dout) {
    int bid = blockIdx.x, tid = threadIdx.x;
    if (bid < PRO_LN) {
        int wv = tid >> 6, lane = tid & 63;
        int row = bid * 4 + wv;  // < 8208
        int t = row % 1026, b = row / 1026;
        u16* out = h1 + (size_t)row * CCH;
        if (t == 1025) {
#pragma unroll
            for (int i = 0; i < 6; i++) out[lane + 64 * i] = 0;
            return;
        }
        ln_from_f32(x + ((size_t)b * 1025 + t) * CCH, n1w, n1b, out, lane);
    } else if (bid < PRO_LN + PRO_CVT) {
        size_t off = ((size_t)(bid - PRO_LN) * 256 + tid) * 8;
        if (off >= W_TOTAL) return;
        const float* src;
        size_t base;
        if (off < W_PROJ)       { src = qkv_w;  base = W_QKV; }
        else if (off < W_POOL)  { src = proj_w; base = W_PROJ; }
        else if (off < W_FC1)   { src = pool_w; base = W_POOL; }
        else if (off < W_FC2)   { src = fc1_w;  base = W_FC1; }
        else                    { src = fc2_w;  base = W_FC2; }
        size_t rel = off - base;
        float4 a = *(const float4*)(src + rel);
        float4 b = *(const float4*)(src + rel + 4);
        uint4 o;
        o.x = (u32)f2b(a.x) | ((u32)f2b(a.y) << 16);
        o.y = (u32)f2b(a.z) | ((u32)f2b(a.w) << 16);
        o.z = (u32)f2b(b.x) | ((u32)f2b(b.y) << 16);
        o.w = (u32)f2b(b.z) | ((u32)f2b(b.w) << 16);
        *(uint4*)(wb + off) = o;
    } else {
        size_t idx = ((size_t)(bid - PRO_LN - PRO_CVT) * 256 + tid) * 4;
        *(float4*)(dout + idx) = make_float4(0.f, 0.f, 0.f, 0.f);
    }
}

// ---------------- midk: LN2 (in-place) || zero(tokf) -------------------------
#define MID_LN 2050
#define MID_ZERO 768
__global__ __launch_bounds__(256) void midk(u16* __restrict__ h,
                                            const float* __restrict__ n2w,
                                            const float* __restrict__ n2b,
                                            float* __restrict__ tokf) {
    int bid = blockIdx.x, tid = threadIdx.x;
    if (bid < MID_LN) {
        int wv = tid >> 6, lane = tid & 63;
        int row = bid * 4 + wv;  // < 8200
        int b = row / 1025, t = row % 1025;
        u16* p = h + ((size_t)b * 1026 + t) * CCH;
        ln_from_b16(p, n2w, n2b, p, lane);
    } else {
        size_t idx = ((size_t)(bid - MID_LN) * 256 + tid) * 4;
        *(float4*)(tokf + idx) = make_float4(0.f, 0.f, 0.f, 0.f);
    }
}

// h3 = LN3(concat(h2[:,0] (bf16), tokf (fp32, pool bias included)))
__global__ __launch_bounds__(64) void ln3_concat(const u16* __restrict__ h2,
                                                 const float* __restrict__ tokf,
                                                 const float* __restrict__ w,
                                                 const float* __restrict__ bb,
                                                 u16* __restrict__ h3) {
    int row = blockIdx.x;  // b*257 + t
    int b = row / 257, t = row % 257;
    int lane = threadIdx.x;
    u16* out = h3 + (size_t)row * CCH;
    if (t == 0) {
        ln_from_b16(h2 + (size_t)b * 1026 * CCH, w, bb, out, lane);
    } else {
        ln_from_f32(tokf + ((size_t)b * 256 + (t - 1)) * CCH, w, bb, out, lane);
    }
}

// ---------------- MFMA GEMM (bf16 A, bf16 pre-converted weights) -------------
template <int TN, bool GATHER, int SPLITK, bool BIAS, bool GELU_ACT, bool RES,
          bool ATOMIC>
__global__ __launch_bounds__(256) void gemm_mf(const u16* __restrict__ A,
                                               int lda,
                                               const u16* __restrict__ Bwb,
                                               const float* __restrict__ bias,
                                               const u16* __restrict__ Res,
                                               void* __restrict__ Yv, int M,
                                               int N, int K) {
    __shared__ u16 Asl[128 * 40];
    __shared__ u16 Bsl[TN * 40];
    const int tid = threadIdx.x;
    const int wave = tid >> 6, lane = tid & 63;
    const int quad = lane >> 4, l15 = lane & 15;
    const int m0 = blockIdx.y * 128, n0 = blockIdx.x * TN;
    const int kp = (SPLITK > 1) ? blockIdx.z : 0;
    const int KS = K / SPLITK;
    const int kbase = kp * KS;

    f32x4 acc[2][TN / 16];
#pragma unroll
    for (int i = 0; i < 2; i++)
#pragma unroll
        for (int j = 0; j < TN / 16; j++) acc[i][j] = (f32x4){0.f, 0.f, 0.f, 0.f};

    for (int kt = 0; kt < KS; kt += 32) {
        const int kk = kbase + kt;
#pragma unroll
        for (int L = 0; L < 2; L++) {
            int linear = L * 256 + tid;
            int row = linear >> 2, seg = linear & 3;
            int kf = kk + seg * 8;
            const u16* src;
            if (GATHER) {
                int m = m0 + row;
                int b = m >> 8, w = m & 255;
                int j = kf / 384, rem = kf - j * 384;
                int pr = 2 * (w >> 4) + j / 3 - 1;
                int pc = 2 * (w & 15) + j % 3 - 1;
                int tok = (pr >= 0 && pr < 32 && pc >= 0 && pc < 32)
                              ? (32 * pr + pc + 1)
                              : 1024;
                src = A + ((size_t)b * 1026 + tok) * 384 + rem;
            } else {
                int m = m0 + row;
                if (m >= M) m = M - 1;
                src = A + (size_t)m * lda + kf;
            }
            *(uint4*)(&Asl[row * 40 + seg * 8]) = *(const uint4*)src;
        }
#pragma unroll
        for (int L = 0; L < TN / 64; L++) {
            int linear = L * 256 + tid;
            int row = linear >> 2, seg = linear & 3;
            *(uint4*)(&Bsl[row * 40 + seg * 8]) =
                *(const uint4*)(Bwb + (size_t)(n0 + row) * K + kk + seg * 8);
        }
        __syncthreads();
        s16x8 afr[2], bfr[TN / 16];
#pragma unroll
        for (int ms = 0; ms < 2; ms++)
            afr[ms] = *(const s16x8*)(&Asl[(wave * 32 + ms * 16 + l15) * 40 +
                                           quad * 8]);
#pragma unroll
        for (int ns = 0; ns < TN / 16; ns++)
            bfr[ns] = *(const s16x8*)(&Bsl[(ns * 16 + l15) * 40 + quad * 8]);
#pragma unroll
        for (int ms = 0; ms < 2; ms++)
#pragma unroll
            for (int ns = 0; ns < TN / 16; ns++)
                acc[ms][ns] = __builtin_amdgcn_mfma_f32_16x16x32_bf16(
                    afr[ms], bfr[ns], acc[ms][ns], 0, 0, 0);
        __syncthreads();
    }
#pragma unroll
    for (int ms = 0; ms < 2; ms++) {
#pragma unroll
        for (int ns = 0; ns < TN / 16; ns++) {
            int n = n0 + ns * 16 + l15;
#pragma unroll
            for (int i = 0; i < 4; i++) {
                int m = m0 + wave * 32 + ms * 16 + quad * 4 + i;
                if (m >= M) continue;
                float v = acc[ms][ns][i];
                if (BIAS && (SPLITK == 1 || kp == 0)) v += bias[n];
                if (RES) v += b2f(Res[(size_t)m * N + n]);
                if (GELU_ACT) v = 0.5f * v * (1.f + erff(v * 0.70710678118f));
                if (ATOMIC)
                    atomicAdd((float*)Yv + (size_t)m * N + n, v);
                else
                    ((u16*)Yv)[(size_t)m * N + n] = f2b(v);
            }
        }
    }
}

// ---------------- fused attention: patch + cls, 1024 threads -----------------
// Blocks [0,1536): patch — 16 dual-query waves/block (32 queries). Per-wave
//   code identical to the proven round-11/13 attn_patch (qsh sliced by wave).
// Blocks [1536,1584): cls — verbatim proven round-9 1024-thread kernel.
#define APATCH 1536
__global__ __launch_bounds__(1024) void attn_all(u16* __restrict__ qkv) {
    __shared__ union SM {
        float qshp[16][2][64];  // patch: per-wave q pair
        struct {
            float sc[1026];
            float qsh[64];
            float redmax[16], redsum[16];
            float pv[16][64];
        } c;
    } sm;
    int tid = threadIdx.x, lane = tid & 63, wv = tid >> 6;  // wv 0..15

    if (blockIdx.x < APATCH) {
        // ---------------- patch mode (per-wave, as proven) ----------------
        int pairIdx = blockIdx.x * 16 + wv;  // [0, 24576)
        int idx = pairIdx & 511;
        int hb = pairIdx >> 9;
        int h = hb % 6, b = hb / 6;
        int hl = lane >> 5, l5 = lane & 31;
        int p0 = idx * 2;
        int p = p0 | hl;  // p0 even
        int r = p >> 5, c = p & 31;
        int rlo, rhi, clo, chi;
        if (r & 1) { rlo = (r - 2 < 0) ? 0 : r - 2; rhi = (r + 2 > 31) ? 31 : r + 2; }
        else       { rlo = (r - 1 < 0) ? 0 : r - 1; rhi = (r + 1 > 31) ? 31 : r + 1; }
        if (c & 1) { clo = (c - 2 < 0) ? 0 : c - 2; chi = (c + 2 > 31) ? 31 : c + 2; }
        else       { clo = (c - 1 < 0) ? 0 : c - 1; chi = (c + 1 > 31) ? 31 : c + 1; }
        int nr = rhi - rlo + 1, nc = chi - clo + 1;
        int nk = nr * nc + 1;  // + CLS at slot 0 (per half)
        int tok = 0;           // slot 0 = CLS (token 0)
        if (l5 >= 1 && l5 < nk) {
            int jj = l5 - 1;
            tok = 1 + ((rlo + jj / nc) << 5) + (clo + jj % nc);
        }
        u16* base = qkv + (size_t)b * 1026 * 1152 + h * 64;
        sm.qshp[wv][0][lane] = b2f(base[(size_t)(1 + p0) * 1152 + lane]);
        sm.qshp[wv][1][lane] = b2f(base[(size_t)(2 + p0) * 1152 + lane]);
        __syncthreads();
        float sc = NEG_BIG;
        if (l5 < nk) {
            const u16* krow = base + (size_t)tok * 1152 + 384;
            float acc = 0.f;
#pragma unroll
            for (int d0 = 0; d0 < 64; d0 += 8)
                acc += dot8(sm.qshp[wv][hl], d0, *(const uint4*)(krow + d0));
            sc = acc * SCALE;
        }
        float mx = fmaxf(half_max(sc), 0.f);  // per-half max, incl pad logit 0
        float pe = (l5 < nk) ? expf(sc - mx) : 0.f;
        float Z = half_sum(pe) + expf(-mx);  // pad key: wt exp(-mx), value 0
        // PV: each half its own query; lane covers dims 2*l5, 2*l5+1.
        float o0 = 0.f, o1 = 0.f;
        for (int j = 0; j < nk; j++) {
            int t = __shfl(tok, (hl << 5) | j, 64);
            float wj = __shfl(pe, (hl << 5) | j, 64);
            u32 vv = *(const u32*)(base + (size_t)t * 1152 + 768 + 2 * l5);
            o0 += wj * b2f((u16)vv);
            o1 += wj * b2f((u16)(vv >> 16));
        }
        float zi = 1.f / Z;
        u32 packed = (u32)f2b(o0 * zi) | ((u32)f2b(o1 * zi) << 16);
        *(u32*)(base + (size_t)(1 + p) * 1152 + 2 * l5) = packed;
    } else {
        // ---------------- cls mode (verbatim proven round-9) ----------------
        int idx = blockIdx.x - APATCH;  // [0,48)
        int h = idx % 6, b = idx / 6;
        u16* base = qkv + (size_t)b * 1026 * 1152 + h * 64;
        if (tid < 64) sm.c.qsh[tid] = b2f(base[tid]);
        __syncthreads();
        for (int key = tid; key < 1026; key += 1024) {
            const u16* krow = base + (size_t)key * 1152 + 384;
            float acc = 0.f;
#pragma unroll
            for (int d0 = 0; d0 < 64; d0 += 8)
                acc += dot8(sm.c.qsh, d0, *(const uint4*)(krow + d0));
            sm.c.sc[key] = acc * SCALE;
        }
        __syncthreads();
        float lm = NEG_BIG;
        for (int key = tid; key < 1026; key += 1024)
            lm = fmaxf(lm, sm.c.sc[key]);
        lm = wave_max(lm);
        if (lane == 0) sm.c.redmax[wv] = lm;
        __syncthreads();
        float mx = NEG_BIG;
#pragma unroll
        for (int i = 0; i < 16; i++) mx = fmaxf(mx, sm.c.redmax[i]);
        float lsum = 0.f;
        for (int key = tid; key < 1026; key += 1024) {
            float e = expf(sm.c.sc[key] - mx);
            sm.c.sc[key] = e;
            lsum += e;
        }
        lsum = wave_sum(lsum);
        if (lane == 0) sm.c.redsum[wv] = lsum;
        __syncthreads();
        float Z = 0.f;
#pragma unroll
        for (int i = 0; i < 16; i++) Z += sm.c.redsum[i];
        float acc = 0.f;
        for (int key = wv; key < 1026; key += 16)
            acc += sm.c.sc[key] * b2f(base[(size_t)key * 1152 + 768 + lane]);
        sm.c.pv[wv][lane] = acc;
        __syncthreads();
        if (tid < 64) {
            float s = 0.f;
#pragma unroll
            for (int w2 = 0; w2 < 16; w2++) s += sm.c.pv[w2][tid];
            base[tid] = f2b(s / Z);
            base[(size_t)1025 * 1152 + tid] = 0;  // att pad row (q-cols)
        }
    }
}

extern "C" void kernel_launch(void* const* d_in, const int* in_sizes, int n_in,
                              void* d_out, int out_size, void* d_ws,
                              size_t ws_size, hipStream_t stream) {
    const float* x      = (const float*)d_in[0];
    const float* n1w    = (const float*)d_in[1];
    const float* n1b    = (const float*)d_in[2];
    const float* qkv_w  = (const float*)d_in[3];
    const float* proj_w = (const float*)d_in[4];
    const float* proj_b = (const float*)d_in[5];
    const float* n2w    = (const float*)d_in[6];
    const float* n2b    = (const float*)d_in[7];
    const float* pool_w = (const float*)d_in[8];
    const float* pool_b = (const float*)d_in[9];
    const float* n3w    = (const float*)d_in[10];
    const float* n3b    = (const float*)d_in[11];
    const float* fc1_w  = (const float*)d_in[12];
    const float* fc1_b  = (const float*)d_in[13];
    const float* fc2_w  = (const float*)d_in[14];
    const float* fc2_b  = (const float*)d_in[15];

    u16* ws = (u16*)d_ws;
    u16* h1    = ws;                      // 8208*384
    u16* qkvb  = ws + 3151872;            // 8208*1152
    u16* wb    = ws + 12607488;           // 3,096,576 bf16 weights
    float* tokf = (float*)qkvb;           // 2048*384 fp32 (reuse after proj)
    u16* h3    = qkvb + 1572864;          // 2056*384
    u16* mlp1  = qkvb + 2362368;          // 2056*1536

    // 0. prologue: LN1 || weight cvt || zero d_out (split-K accumulator)
    prologue<<<PRO_LN + PRO_CVT + PRO_ZERO, 256, 0, stream>>>(
        x, n1w, n1b, h1, qkv_w, proj_w, pool_w, fc1_w, fc2_w, wb,
        (float*)d_out);
    // 1. qkv = h1 @ qkv_w^T  (8208 x 1152 x 384), 128x128 tile
    gemm_mf<128, false, 1, false, false, false, false>
        <<<dim3(1152 / 128, 65), 256, 0, stream>>>(h1, 384, wb + W_QKV,
                                                   nullptr, nullptr, qkvb,
                                                   8208, 1152, 384);
    // 2. fused attention (patch + cls) -> att into q-columns of qkvb
    attn_all<<<APATCH + 48, 1024, 0, stream>>>(qkvb);
    // 3. h1 = h1 + att @ proj_w^T + proj_b  (A = qkvb q-cols, lda=1152)
    gemm_mf<64, false, 1, true, false, true, false>
        <<<dim3(384 / 64, 65), 256, 0, stream>>>(qkvb, 1152, wb + W_PROJ,
                                                 proj_b, h1, h1, 8208, 384,
                                                 384);
    // 4. midk: LN2 in-place || zero tokf (aliases qkvb — dead after proj)
    midk<<<MID_LN + MID_ZERO, 256, 0, stream>>>(h1, n2w, n2b, tokf);
    // 5. tokf += gather(h1) @ pool_w^T (+ pool_b on kp==0)  split-K=4
    gemm_mf<64, true, 4, true, false, false, true>
        <<<dim3(384 / 64, 16, 4), 256, 0, stream>>>(h1, 384, wb + W_POOL,
                                                    pool_b, nullptr, tokf,
                                                    2048, 384, 3456);
    // 6. h3 = LN3(concat(h1[:,0], tokf))
    ln3_concat<<<8 * 257, 64, 0, stream>>>(h1, tokf, n3w, n3b, h3);
    // 7. mlp1 = gelu(h3 @ fc1_w^T + fc1_b)  (2056 x 1536 x 384)
    gemm_mf<64, false, 1, true, true, false, false>
        <<<dim3(1536 / 64, 17), 256, 0, stream>>>(h3, 384, wb + W_FC1, fc1_b,
                                                  nullptr, mlp1, 2056, 1536,
                                                  384);
    // 8. d_out += mlp1 @ fc2_w^T (+ fc2_b on kp==0)  split-K=4, fp32 out
    gemm_mf<64, false, 4, true, false, false, true>
        <<<dim3(384 / 64, 17, 4), 256, 0, stream>>>(mlp1, 1536, wb + W_FC2,
                                                    fc2_b, nullptr, d_out,
                                                    2056, 384, 1536);
}

// Round 15
// 284.792 us; speedup vs baseline: 1.0922x; 1.0922x over previous
//
#include <hip/hip_runtime.h>

// ConvAttention forward, MI355X. fp32 I/O, bf16 intermediates, MFMA GEMMs.
// PROVEN round-13 state (best measured: 284 us). Structure:
//   prologue = LN1 || cvt_weights(fp32->bf16) || zero(d_out)
//   qkv GEMM (128x128 tile) -> attn_patch (dual-query, half-wave PV)
//   -> attn_cls (16 waves) -> proj GEMM (+residual) -> midk (LN2 || zero tokf)
//   -> pool GEMM (fused 3x3 gather, split-K=4, atomic) -> ln3 -> fc1 -> fc2.
// GEMM: 128xTN tile, 4 waves, BK=32, LDS row pitch 40 (conflict-free b128).
// Negative results worth keeping (measured): BK=64 regressed (-18 us,
// occupancy loss > barrier savings); grouping attention waves into 256/1024-
// thread blocks regressed 1.7x (barrier tail-gating + L1 thrash).
// ws (u16 units): h1 [0, 3151872) ; qkvb [3151872, 12607488) ;
//   wb [12607488, 15704064)  (bf16 weights: qkv|proj|pool|fc1|fc2)
//   att = q-cols of qkvb (lda 1152). After proj, qkvb region reused:
//   tokf (fp32) at qkvb+0 ; h3 at qkvb+1572864 ; mlp1 at qkvb+2362368.
// NOTE: tokf zeroing rides midk, stream-ordered AFTER proj (qkvb alias).

typedef unsigned short u16;
typedef unsigned int u32;
typedef short s16x8 __attribute__((ext_vector_type(8)));
typedef float f32x4 __attribute__((ext_vector_type(4)));

__device__ __forceinline__ float b2f(u16 u) {
    return __uint_as_float(((u32)u) << 16);
}
__device__ __forceinline__ u16 f2b(float f) {
    u32 u = __float_as_uint(f);
    return (u16)((u + 0x7FFFu + ((u >> 16) & 1u)) >> 16);  // RTNE
}
__device__ __forceinline__ float wave_sum(float v) {
#pragma unroll
    for (int o = 32; o > 0; o >>= 1) v += __shfl_xor(v, o, 64);
    return v;
}
__device__ __forceinline__ float wave_max(float v) {
#pragma unroll
    for (int o = 32; o > 0; o >>= 1) v = fmaxf(v, __shfl_xor(v, o, 64));
    return v;
}
__device__ __forceinline__ float half_sum(float v) {
#pragma unroll
    for (int o = 16; o > 0; o >>= 1) v += __shfl_xor(v, o, 64);
    return v;
}
__device__ __forceinline__ float half_max(float v) {
#pragma unroll
    for (int o = 16; o > 0; o >>= 1) v = fmaxf(v, __shfl_xor(v, o, 64));
    return v;
}
__device__ __forceinline__ float dot8(const float* qsh, int d0, uint4 u) {
    return qsh[d0 + 0] * b2f((u16)(u.x)) + qsh[d0 + 1] * b2f((u16)(u.x >> 16)) +
           qsh[d0 + 2] * b2f((u16)(u.y)) + qsh[d0 + 3] * b2f((u16)(u.y >> 16)) +
           qsh[d0 + 4] * b2f((u16)(u.z)) + qsh[d0 + 5] * b2f((u16)(u.z >> 16)) +
           qsh[d0 + 6] * b2f((u16)(u.w)) + qsh[d0 + 7] * b2f((u16)(u.w >> 16));
}

#define CCH 384
#define SCALE 0.40824829046386302f  // H^-0.5 = 6^-0.5
#define NEG_BIG (-1e30f)

// weight segment offsets in wb (u16 units)
#define W_QKV 0
#define W_PROJ 442368
#define W_POOL 589824
#define W_FC1 1916928
#define W_FC2 2506752
#define W_TOTAL 3096576

// ---------------- LN row helpers (per-wave, no block barriers) ---------------
__device__ __forceinline__ void ln_from_f32(const float* in, const float* w,
                                            const float* bb, u16* out,
                                            int lane) {
    float v[6];
    float s = 0.f, ss = 0.f;
#pragma unroll
    for (int i = 0; i < 6; i++) {
        v[i] = in[lane + 64 * i];
        s += v[i];
        ss += v[i] * v[i];
    }
    s = wave_sum(s);
    ss = wave_sum(ss);
    float mu = s * (1.f / 384.f);
    float var = ss * (1.f / 384.f) - mu * mu;
    float inv = rsqrtf(var + 1e-5f);
#pragma unroll
    for (int i = 0; i < 6; i++) {
        int c = lane + 64 * i;
        out[c] = f2b((v[i] - mu) * inv * w[c] + bb[c]);
    }
}
__device__ __forceinline__ void ln_from_b16(const u16* in, const float* w,
                                            const float* bb, u16* out,
                                            int lane) {
    float v[6];
    float s = 0.f, ss = 0.f;
#pragma unroll
    for (int i = 0; i < 6; i++) {
        v[i] = b2f(in[lane + 64 * i]);
        s += v[i];
        ss += v[i] * v[i];
    }
    s = wave_sum(s);
    ss = wave_sum(ss);
    float mu = s * (1.f / 384.f);
    float var = ss * (1.f / 384.f) - mu * mu;
    float inv = rsqrtf(var + 1e-5f);
#pragma unroll
    for (int i = 0; i < 6; i++) {
        int c = lane + 64 * i;
        out[c] = f2b((v[i] - mu) * inv * w[c] + bb[c]);
    }
}

// ---------------- prologue: LN1 || cvt_weights || zero(d_out) ----------------
#define PRO_LN 2052
#define PRO_CVT 1512
#define PRO_ZERO 771
__global__ __launch_bounds__(256) void prologue(
    const float* __restrict__ x, const float* __restrict__ n1w,
    const float* __restrict__ n1b, u16* __restrict__ h1,
    const float* __restrict__ qkv_w, const float* __restrict__ proj_w,
    const float* __restrict__ pool_w, const float* __restrict__ fc1_w,
    const float* __restrict__ fc2_w, u16* __restrict__ wb,
    float* __restrict__ dout) {
    int bid = blockIdx.x, tid = threadIdx.x;
    if (bid < PRO_LN) {
        int wv = tid >> 6, lane = tid & 63;
        int row = bid * 4 + wv;  // < 8208
        int t = row % 1026, b = row / 1026;
        u16* out = h1 + (size_t)row * CCH;
        if (t == 1025) {
#pragma unroll
            for (int i = 0; i < 6; i++) out[lane + 64 * i] = 0;
            return;
        }
        ln_from_f32(x + ((size_t)b * 1025 + t) * CCH, n1w, n1b, out, lane);
    } else if (bid < PRO_LN + PRO_CVT) {
        size_t off = ((size_t)(bid - PRO_LN) * 256 + tid) * 8;
        if (off >= W_TOTAL) return;
        const float* src;
        size_t base;
        if (off < W_PROJ)       { src = qkv_w;  base = W_QKV; }
        else if (off < W_POOL)  { src = proj_w; base = W_PROJ; }
        else if (off < W_FC1)   { src = pool_w; base = W_POOL; }
        else if (off < W_FC2)   { src = fc1_w;  base = W_FC1; }
        else                    { src = fc2_w;  base = W_FC2; }
        size_t rel = off - base;
        float4 a = *(const float4*)(src + rel);
        float4 b = *(const float4*)(src + rel + 4);
        uint4 o;
        o.x = (u32)f2b(a.x) | ((u32)f2b(a.y) << 16);
        o.y = (u32)f2b(a.z) | ((u32)f2b(a.w) << 16);
        o.z = (u32)f2b(b.x) | ((u32)f2b(b.y) << 16);
        o.w = (u32)f2b(b.z) | ((u32)f2b(b.w) << 16);
        *(uint4*)(wb + off) = o;
    } else {
        size_t idx = ((size_t)(bid - PRO_LN - PRO_CVT) * 256 + tid) * 4;
        *(float4*)(dout + idx) = make_float4(0.f, 0.f, 0.f, 0.f);
    }
}

// ---------------- midk: LN2 (in-place) || zero(tokf) -------------------------
#define MID_LN 2050
#define MID_ZERO 768
__global__ __launch_bounds__(256) void midk(u16* __restrict__ h,
                                            const float* __restrict__ n2w,
                                            const float* __restrict__ n2b,
                                            float* __restrict__ tokf) {
    int bid = blockIdx.x, tid = threadIdx.x;
    if (bid < MID_LN) {
        int wv = tid >> 6, lane = tid & 63;
        int row = bid * 4 + wv;  // < 8200
        int b = row / 1025, t = row % 1025;
        u16* p = h + ((size_t)b * 1026 + t) * CCH;
        ln_from_b16(p, n2w, n2b, p, lane);
    } else {
        size_t idx = ((size_t)(bid - MID_LN) * 256 + tid) * 4;
        *(float4*)(tokf + idx) = make_float4(0.f, 0.f, 0.f, 0.f);
    }
}

// h3 = LN3(concat(h2[:,0] (bf16), tokf (fp32, pool bias included)))
__global__ __launch_bounds__(64) void ln3_concat(const u16* __restrict__ h2,
                                                 const float* __restrict__ tokf,
                                                 const float* __restrict__ w,
                                                 const float* __restrict__ bb,
                                                 u16* __restrict__ h3) {
    int row = blockIdx.x;  // b*257 + t
    int b = row / 257, t = row % 257;
    int lane = threadIdx.x;
    u16* out = h3 + (size_t)row * CCH;
    if (t == 0) {
        ln_from_b16(h2 + (size_t)b * 1026 * CCH, w, bb, out, lane);
    } else {
        ln_from_f32(tokf + ((size_t)b * 256 + (t - 1)) * CCH, w, bb, out, lane);
    }
}

// ---------------- MFMA GEMM (bf16 A, bf16 pre-converted weights) -------------
// Y[M,N] = act(A[M,K]bf16 @ Wb[N,K]bf16^T + bias) (+Res bf16)
// Tile 128xTN (TN in {64,128}), 4 waves, BK=32. LDS rows pad 40.
// GATHER: A row m gathers 3x3 window of h2 (pool). SPLITK: blockIdx.z splits K;
// ATOMIC: fp32 atomicAdd into Yv (zero-initialized), bias added by kp==0.
template <int TN, bool GATHER, int SPLITK, bool BIAS, bool GELU_ACT, bool RES,
          bool ATOMIC>
__global__ __launch_bounds__(256) void gemm_mf(const u16* __restrict__ A,
                                               int lda,
                                               const u16* __restrict__ Bwb,
                                               const float* __restrict__ bias,
                                               const u16* __restrict__ Res,
                                               void* __restrict__ Yv, int M,
                                               int N, int K) {
    __shared__ u16 Asl[128 * 40];
    __shared__ u16 Bsl[TN * 40];
    const int tid = threadIdx.x;
    const int wave = tid >> 6, lane = tid & 63;
    const int quad = lane >> 4, l15 = lane & 15;
    const int m0 = blockIdx.y * 128, n0 = blockIdx.x * TN;
    const int kp = (SPLITK > 1) ? blockIdx.z : 0;
    const int KS = K / SPLITK;
    const int kbase = kp * KS;

    f32x4 acc[2][TN / 16];
#pragma unroll
    for (int i = 0; i < 2; i++)
#pragma unroll
        for (int j = 0; j < TN / 16; j++) acc[i][j] = (f32x4){0.f, 0.f, 0.f, 0.f};

    for (int kt = 0; kt < KS; kt += 32) {
        const int kk = kbase + kt;
#pragma unroll
        for (int L = 0; L < 2; L++) {
            int linear = L * 256 + tid;
            int row = linear >> 2, seg = linear & 3;
            int kf = kk + seg * 8;
            const u16* src;
            if (GATHER) {
                int m = m0 + row;
                int b = m >> 8, w = m & 255;
                int j = kf / 384, rem = kf - j * 384;
                int pr = 2 * (w >> 4) + j / 3 - 1;
                int pc = 2 * (w & 15) + j % 3 - 1;
                int tok = (pr >= 0 && pr < 32 && pc >= 0 && pc < 32)
                              ? (32 * pr + pc + 1)
                              : 1024;
                src = A + ((size_t)b * 1026 + tok) * 384 + rem;
            } else {
                int m = m0 + row;
                if (m >= M) m = M - 1;
                src = A + (size_t)m * lda + kf;
            }
            *(uint4*)(&Asl[row * 40 + seg * 8]) = *(const uint4*)src;
        }
#pragma unroll
        for (int L = 0; L < TN / 64; L++) {
            int linear = L * 256 + tid;
            int row = linear >> 2, seg = linear & 3;
            *(uint4*)(&Bsl[row * 40 + seg * 8]) =
                *(const uint4*)(Bwb + (size_t)(n0 + row) * K + kk + seg * 8);
        }
        __syncthreads();
        s16x8 afr[2], bfr[TN / 16];
#pragma unroll
        for (int ms = 0; ms < 2; ms++)
            afr[ms] = *(const s16x8*)(&Asl[(wave * 32 + ms * 16 + l15) * 40 +
                                           quad * 8]);
#pragma unroll
        for (int ns = 0; ns < TN / 16; ns++)
            bfr[ns] = *(const s16x8*)(&Bsl[(ns * 16 + l15) * 40 + quad * 8]);
#pragma unroll
        for (int ms = 0; ms < 2; ms++)
#pragma unroll
            for (int ns = 0; ns < TN / 16; ns++)
                acc[ms][ns] = __builtin_amdgcn_mfma_f32_16x16x32_bf16(
                    afr[ms], bfr[ns], acc[ms][ns], 0, 0, 0);
        __syncthreads();
    }
#pragma unroll
    for (int ms = 0; ms < 2; ms++) {
#pragma unroll
        for (int ns = 0; ns < TN / 16; ns++) {
            int n = n0 + ns * 16 + l15;
#pragma unroll
            for (int i = 0; i < 4; i++) {
                int m = m0 + wave * 32 + ms * 16 + quad * 4 + i;
                if (m >= M) continue;
                float v = acc[ms][ns][i];
                if (BIAS && (SPLITK == 1 || kp == 0)) v += bias[n];
                if (RES) v += b2f(Res[(size_t)m * N + n]);
                if (GELU_ACT) v = 0.5f * v * (1.f + erff(v * 0.70710678118f));
                if (ATOMIC)
                    atomicAdd((float*)Yv + (size_t)m * N + n, v);
                else
                    ((u16*)Yv)[(size_t)m * N + n] = f2b(v);
            }
        }
    }
}

// ---------------- sparse window attention, patch queries (dual) --------------
// One wave handles queries p0=2*idx and p0+1: lanes 0..31 score q0's keys,
// lanes 32..63 score q1's. Half-wave softmax. PV also half-wave: each half
// does its own query, 2 dims/lane (u32 V loads). Output -> dead q-cols.
// 64-thread blocks are a measured optimum (256/1024-thr grouping regressed).
__global__ __launch_bounds__(64) void attn_patch(u16* __restrict__ qkv) {
    int bid = blockIdx.x;
    int idx = bid & 511;
    int hb = bid >> 9;
    int h = hb % 6, b = hb / 6;
    int lane = threadIdx.x;
    int hl = lane >> 5, l5 = lane & 31;
    int p0 = idx * 2;
    int p = p0 | hl;  // p0 even
    int r = p >> 5, c = p & 31;
    int rlo, rhi, clo, chi;
    if (r & 1) { rlo = (r - 2 < 0) ? 0 : r - 2; rhi = (r + 2 > 31) ? 31 : r + 2; }
    else       { rlo = (r - 1 < 0) ? 0 : r - 1; rhi = (r + 1 > 31) ? 31 : r + 1; }
    if (c & 1) { clo = (c - 2 < 0) ? 0 : c - 2; chi = (c + 2 > 31) ? 31 : c + 2; }
    else       { clo = (c - 1 < 0) ? 0 : c - 1; chi = (c + 1 > 31) ? 31 : c + 1; }
    int nr = rhi - rlo + 1, nc = chi - clo + 1;
    int nk = nr * nc + 1;  // + CLS at slot 0 (per half)
    int tok = 0;           // slot 0 = CLS (token 0)
    if (l5 >= 1 && l5 < nk) {
        int jj = l5 - 1;
        tok = 1 + ((rlo + jj / nc) << 5) + (clo + jj % nc);
    }
    u16* base = qkv + (size_t)b * 1026 * 1152 + h * 64;
    __shared__ float qsh[2][64];
    qsh[0][lane] = b2f(base[(size_t)(1 + p0) * 1152 + lane]);
    qsh[1][lane] = b2f(base[(size_t)(2 + p0) * 1152 + lane]);
    __syncthreads();
    float sc = NEG_BIG;
    if (l5 < nk) {
        const u16* krow = base + (size_t)tok * 1152 + 384;
        float acc = 0.f;
#pragma unroll
        for (int d0 = 0; d0 < 64; d0 += 8)
            acc += dot8(qsh[hl], d0, *(const uint4*)(krow + d0));
        sc = acc * SCALE;
    }
    float mx = fmaxf(half_max(sc), 0.f);  // per-half max, incl pad logit 0
    float pe = (l5 < nk) ? expf(sc - mx) : 0.f;
    float Z = half_sum(pe) + expf(-mx);  // pad key: weight exp(-mx), value 0
    // PV: each half handles its own query; lane covers dims 2*l5, 2*l5+1.
    float o0 = 0.f, o1 = 0.f;
    for (int j = 0; j < nk; j++) {
        int t = __shfl(tok, (hl << 5) | j, 64);
        float wj = __shfl(pe, (hl << 5) | j, 64);
        u32 vv = *(const u32*)(base + (size_t)t * 1152 + 768 + 2 * l5);
        o0 += wj * b2f((u16)vv);
        o1 += wj * b2f((u16)(vv >> 16));
    }
    float zi = 1.f / Z;
    u32 packed = (u32)f2b(o0 * zi) | ((u32)f2b(o1 * zi) << 16);
    *(u32*)(base + (size_t)(1 + p) * 1152 + 2 * l5) = packed;
}

// ---------------- dense attention for CLS query (row 0) ----------------------
// 16 waves: per-thread key dots; block softmax; PV by (wave=key%16, lane=dim).
__global__ __launch_bounds__(1024) void attn_cls(u16* __restrict__ qkv) {
    int h = blockIdx.x % 6, b = blockIdx.x / 6;
    u16* base = qkv + (size_t)b * 1026 * 1152 + h * 64;
    int tid = threadIdx.x, lane = tid & 63, wv = tid >> 6;  // wv 0..15
    __shared__ float sc[1026];
    __shared__ float qsh[64];
    __shared__ float redmax[16], redsum[16];
    __shared__ float pv[16][64];
    if (tid < 64) qsh[tid] = b2f(base[tid]);
    __syncthreads();
    for (int key = tid; key < 1026; key += 1024) {
        const u16* krow = base + (size_t)key * 1152 + 384;
        float acc = 0.f;
#pragma unroll
        for (int d0 = 0; d0 < 64; d0 += 8)
            acc += dot8(qsh, d0, *(const uint4*)(krow + d0));
        sc[key] = acc * SCALE;
    }
    __syncthreads();
    float lm = NEG_BIG;
    for (int key = tid; key < 1026; key += 1024) lm = fmaxf(lm, sc[key]);
    lm = wave_max(lm);
    if (lane == 0) redmax[wv] = lm;
    __syncthreads();
    float mx = NEG_BIG;
#pragma unroll
    for (int i = 0; i < 16; i++) mx = fmaxf(mx, redmax[i]);
    float lsum = 0.f;
    for (int key = tid; key < 1026; key += 1024) {
        float e = expf(sc[key] - mx);
        sc[key] = e;
        lsum += e;
    }
    lsum = wave_sum(lsum);
    if (lane == 0) redsum[wv] = lsum;
    __syncthreads();
    float Z = 0.f;
#pragma unroll
    for (int i = 0; i < 16; i++) Z += redsum[i];
    float acc = 0.f;
    for (int key = wv; key < 1026; key += 16)
        acc += sc[key] * b2f(base[(size_t)key * 1152 + 768 + lane]);
    pv[wv][lane] = acc;
    __syncthreads();
    if (tid < 64) {
        float s = 0.f;
#pragma unroll
        for (int w2 = 0; w2 < 16; w2++) s += pv[w2][tid];
        base[tid] = f2b(s / Z);
        base[(size_t)1025 * 1152 + tid] = 0;  // att pad row (q-cols)
    }
}

extern "C" void kernel_launch(void* const* d_in, const int* in_sizes, int n_in,
                              void* d_out, int out_size, void* d_ws,
                              size_t ws_size, hipStream_t stream) {
    const float* x      = (const float*)d_in[0];
    const float* n1w    = (const float*)d_in[1];
    const float* n1b    = (const float*)d_in[2];
    const float* qkv_w  = (const float*)d_in[3];
    const float* proj_w = (const float*)d_in[4];
    const float* proj_b = (const float*)d_in[5];
    const float* n2w    = (const float*)d_in[6];
    const float* n2b    = (const float*)d_in[7];
    const float* pool_w = (const float*)d_in[8];
    const float* pool_b = (const float*)d_in[9];
    const float* n3w    = (const float*)d_in[10];
    const float* n3b    = (const float*)d_in[11];
    const float* fc1_w  = (const float*)d_in[12];
    const float* fc1_b  = (const float*)d_in[13];
    const float* fc2_w  = (const float*)d_in[14];
    const float* fc2_b  = (const float*)d_in[15];

    u16* ws = (u16*)d_ws;
    u16* h1    = ws;                      // 8208*384
    u16* qkvb  = ws + 3151872;            // 8208*1152
    u16* wb    = ws + 12607488;           // 3,096,576 bf16 weights
    float* tokf = (float*)qkvb;           // 2048*384 fp32 (reuse after proj)
    u16* h3    = qkvb + 1572864;          // 2056*384
    u16* mlp1  = qkvb + 2362368;          // 2056*1536

    // 0. prologue: LN1 || weight cvt || zero d_out (split-K accumulator)
    prologue<<<PRO_LN + PRO_CVT + PRO_ZERO, 256, 0, stream>>>(
        x, n1w, n1b, h1, qkv_w, proj_w, pool_w, fc1_w, fc2_w, wb,
        (float*)d_out);
    // 1. qkv = h1 @ qkv_w^T  (8208 x 1152 x 384), 128x128 tile
    gemm_mf<128, false, 1, false, false, false, false>
        <<<dim3(1152 / 128, 65), 256, 0, stream>>>(h1, 384, wb + W_QKV,
                                                   nullptr, nullptr, qkvb,
                                                   8208, 1152, 384);
    // 2. sparse attention -> att into q-columns of qkvb
    attn_patch<<<8 * 6 * 512, 64, 0, stream>>>(qkvb);
    attn_cls<<<8 * 6, 1024, 0, stream>>>(qkvb);
    // 3. h1 = h1 + att @ proj_w^T + proj_b  (A = qkvb q-cols, lda=1152)
    gemm_mf<64, false, 1, true, false, true, false>
        <<<dim3(384 / 64, 65), 256, 0, stream>>>(qkvb, 1152, wb + W_PROJ,
                                                 proj_b, h1, h1, 8208, 384,
                                                 384);
    // 4. midk: LN2 in-place || zero tokf (aliases qkvb — dead after proj)
    midk<<<MID_LN + MID_ZERO, 256, 0, stream>>>(h1, n2w, n2b, tokf);
    // 5. tokf += gather(h1) @ pool_w^T (+ pool_b on kp==0)  split-K=4
    gemm_mf<64, true, 4, true, false, false, true>
        <<<dim3(384 / 64, 16, 4), 256, 0, stream>>>(h1, 384, wb + W_POOL,
                                                    pool_b, nullptr, tokf,
                                                    2048, 384, 3456);
    // 6. h3 = LN3(concat(h1[:,0], tokf))
    ln3_concat<<<8 * 257, 64, 0, stream>>>(h1, tokf, n3w, n3b, h3);
    // 7. mlp1 = gelu(h3 @ fc1_w^T + fc1_b)  (2056 x 1536 x 384)
    gemm_mf<64, false, 1, true, true, false, false>
        <<<dim3(1536 / 64, 17), 256, 0, stream>>>(h3, 384, wb + W_FC1, fc1_b,
                                                  nullptr, mlp1, 2056, 1536,
                                                  384);
    // 8. d_out += mlp1 @ fc2_w^T (+ fc2_b on kp==0)  split-K=4, fp32 out
    gemm_mf<64, false, 4, true, false, false, true>
        <<<dim3(384 / 64, 17, 4), 256, 0, stream>>>(mlp1, 1536, wb + W_FC2,
                                                    fc2_b, nullptr, d_out,
                                                    2056, 384, 1536);
}

// Round 16
// 274.547 us; speedup vs baseline: 1.1330x; 1.0373x over previous
//
#include <hip/hip_runtime.h>

// ConvAttention forward, MI355X. fp32 I/O, bf16 intermediates, MFMA GEMMs.
// Round-13 proven structure (284 us) + R16: attn_patch PV loop fixed at 26
// trips (compile-time unroll -> all V-loads issued before the FMA chain;
// j>=nk lanes have pe=0 and tok=0 so extra trips are exact no-ops).
//   prologue = LN1 || cvt_weights(fp32->bf16) || zero(d_out)
//   qkv GEMM (128x128 tile) -> attn_patch (dual-query, half-wave PV)
//   -> attn_cls (16 waves) -> proj GEMM (+residual) -> midk (LN2 || zero tokf)
//   -> pool GEMM (fused 3x3 gather, split-K=4, atomic) -> ln3 -> fc1 -> fc2.
// GEMM: 128xTN tile, 4 waves, BK=32, LDS row pitch 40 (conflict-free b128).
// Negative results worth keeping (measured): BK=64 regressed (-18 us,
// occupancy loss > barrier savings); grouping attention waves into 256/1024-
// thread blocks regressed 1.7x (barrier tail-gating + L1 thrash).
// ws (u16 units): h1 [0, 3151872) ; qkvb [3151872, 12607488) ;
//   wb [12607488, 15704064)  (bf16 weights: qkv|proj|pool|fc1|fc2)
//   att = q-cols of qkvb (lda 1152). After proj, qkvb region reused:
//   tokf (fp32) at qkvb+0 ; h3 at qkvb+1572864 ; mlp1 at qkvb+2362368.
// NOTE: tokf zeroing rides midk, stream-ordered AFTER proj (qkvb alias).

typedef unsigned short u16;
typedef unsigned int u32;
typedef short s16x8 __attribute__((ext_vector_type(8)));
typedef float f32x4 __attribute__((ext_vector_type(4)));

__device__ __forceinline__ float b2f(u16 u) {
    return __uint_as_float(((u32)u) << 16);
}
__device__ __forceinline__ u16 f2b(float f) {
    u32 u = __float_as_uint(f);
    return (u16)((u + 0x7FFFu + ((u >> 16) & 1u)) >> 16);  // RTNE
}
__device__ __forceinline__ float wave_sum(float v) {
#pragma unroll
    for (int o = 32; o > 0; o >>= 1) v += __shfl_xor(v, o, 64);
    return v;
}
__device__ __forceinline__ float wave_max(float v) {
#pragma unroll
    for (int o = 32; o > 0; o >>= 1) v = fmaxf(v, __shfl_xor(v, o, 64));
    return v;
}
__device__ __forceinline__ float half_sum(float v) {
#pragma unroll
    for (int o = 16; o > 0; o >>= 1) v += __shfl_xor(v, o, 64);
    return v;
}
__device__ __forceinline__ float half_max(float v) {
#pragma unroll
    for (int o = 16; o > 0; o >>= 1) v = fmaxf(v, __shfl_xor(v, o, 64));
    return v;
}
__device__ __forceinline__ float dot8(const float* qsh, int d0, uint4 u) {
    return qsh[d0 + 0] * b2f((u16)(u.x)) + qsh[d0 + 1] * b2f((u16)(u.x >> 16)) +
           qsh[d0 + 2] * b2f((u16)(u.y)) + qsh[d0 + 3] * b2f((u16)(u.y >> 16)) +
           qsh[d0 + 4] * b2f((u16)(u.z)) + qsh[d0 + 5] * b2f((u16)(u.z >> 16)) +
           qsh[d0 + 6] * b2f((u16)(u.w)) + qsh[d0 + 7] * b2f((u16)(u.w >> 16));
}

#define CCH 384
#define SCALE 0.40824829046386302f  // H^-0.5 = 6^-0.5
#define NEG_BIG (-1e30f)

// weight segment offsets in wb (u16 units)
#define W_QKV 0
#define W_PROJ 442368
#define W_POOL 589824
#define W_FC1 1916928
#define W_FC2 2506752
#define W_TOTAL 3096576

// ---------------- LN row helpers (per-wave, no block barriers) ---------------
__device__ __forceinline__ void ln_from_f32(const float* in, const float* w,
                                            const float* bb, u16* out,
                                            int lane) {
    float v[6];
    float s = 0.f, ss = 0.f;
#pragma unroll
    for (int i = 0; i < 6; i++) {
        v[i] = in[lane + 64 * i];
        s += v[i];
        ss += v[i] * v[i];
    }
    s = wave_sum(s);
    ss = wave_sum(ss);
    float mu = s * (1.f / 384.f);
    float var = ss * (1.f / 384.f) - mu * mu;
    float inv = rsqrtf(var + 1e-5f);
#pragma unroll
    for (int i = 0; i < 6; i++) {
        int c = lane + 64 * i;
        out[c] = f2b((v[i] - mu) * inv * w[c] + bb[c]);
    }
}
__device__ __forceinline__ void ln_from_b16(const u16* in, const float* w,
                                            const float* bb, u16* out,
                                            int lane) {
    float v[6];
    float s = 0.f, ss = 0.f;
#pragma unroll
    for (int i = 0; i < 6; i++) {
        v[i] = b2f(in[lane + 64 * i]);
        s += v[i];
        ss += v[i] * v[i];
    }
    s = wave_sum(s);
    ss = wave_sum(ss);
    float mu = s * (1.f / 384.f);
    float var = ss * (1.f / 384.f) - mu * mu;
    float inv = rsqrtf(var + 1e-5f);
#pragma unroll
    for (int i = 0; i < 6; i++) {
        int c = lane + 64 * i;
        out[c] = f2b((v[i] - mu) * inv * w[c] + bb[c]);
    }
}

// ---------------- prologue: LN1 || cvt_weights || zero(d_out) ----------------
#define PRO_LN 2052
#define PRO_CVT 1512
#define PRO_ZERO 771
__global__ __launch_bounds__(256) void prologue(
    const float* __restrict__ x, const float* __restrict__ n1w,
    const float* __restrict__ n1b, u16* __restrict__ h1,
    const float* __restrict__ qkv_w, const float* __restrict__ proj_w,
    const float* __restrict__ pool_w, const float* __restrict__ fc1_w,
    const float* __restrict__ fc2_w, u16* __restrict__ wb,
    float* __restrict__ dout) {
    int bid = blockIdx.x, tid = threadIdx.x;
    if (bid < PRO_LN) {
        int wv = tid >> 6, lane = tid & 63;
        int row = bid * 4 + wv;  // < 8208
        int t = row % 1026, b = row / 1026;
        u16* out = h1 + (size_t)row * CCH;
        if (t == 1025) {
#pragma unroll
            for (int i = 0; i < 6; i++) out[lane + 64 * i] = 0;
            return;
        }
        ln_from_f32(x + ((size_t)b * 1025 + t) * CCH, n1w, n1b, out, lane);
    } else if (bid < PRO_LN + PRO_CVT) {
        size_t off = ((size_t)(bid - PRO_LN) * 256 + tid) * 8;
        if (off >= W_TOTAL) return;
        const float* src;
        size_t base;
        if (off < W_PROJ)       { src = qkv_w;  base = W_QKV; }
        else if (off < W_POOL)  { src = proj_w; base = W_PROJ; }
        else if (off < W_FC1)   { src = pool_w; base = W_POOL; }
        else if (off < W_FC2)   { src = fc1_w;  base = W_FC1; }
        else                    { src = fc2_w;  base = W_FC2; }
        size_t rel = off - base;
        float4 a = *(const float4*)(src + rel);
        float4 b = *(const float4*)(src + rel + 4);
        uint4 o;
        o.x = (u32)f2b(a.x) | ((u32)f2b(a.y) << 16);
        o.y = (u32)f2b(a.z) | ((u32)f2b(a.w) << 16);
        o.z = (u32)f2b(b.x) | ((u32)f2b(b.y) << 16);
        o.w = (u32)f2b(b.z) | ((u32)f2b(b.w) << 16);
        *(uint4*)(wb + off) = o;
    } else {
        size_t idx = ((size_t)(bid - PRO_LN - PRO_CVT) * 256 + tid) * 4;
        *(float4*)(dout + idx) = make_float4(0.f, 0.f, 0.f, 0.f);
    }
}

// ---------------- midk: LN2 (in-place) || zero(tokf) -------------------------
#define MID_LN 2050
#define MID_ZERO 768
__global__ __launch_bounds__(256) void midk(u16* __restrict__ h,
                                            const float* __restrict__ n2w,
                                            const float* __restrict__ n2b,
                                            float* __restrict__ tokf) {
    int bid = blockIdx.x, tid = threadIdx.x;
    if (bid < MID_LN) {
        int wv = tid >> 6, lane = tid & 63;
        int row = bid * 4 + wv;  // < 8200
        int b = row / 1025, t = row % 1025;
        u16* p = h + ((size_t)b * 1026 + t) * CCH;
        ln_from_b16(p, n2w, n2b, p, lane);
    } else {
        size_t idx = ((size_t)(bid - MID_LN) * 256 + tid) * 4;
        *(float4*)(tokf + idx) = make_float4(0.f, 0.f, 0.f, 0.f);
    }
}

// h3 = LN3(concat(h2[:,0] (bf16), tokf (fp32, pool bias included)))
__global__ __launch_bounds__(64) void ln3_concat(const u16* __restrict__ h2,
                                                 const float* __restrict__ tokf,
                                                 const float* __restrict__ w,
                                                 const float* __restrict__ bb,
                                                 u16* __restrict__ h3) {
    int row = blockIdx.x;  // b*257 + t
    int b = row / 257, t = row % 257;
    int lane = threadIdx.x;
    u16* out = h3 + (size_t)row * CCH;
    if (t == 0) {
        ln_from_b16(h2 + (size_t)b * 1026 * CCH, w, bb, out, lane);
    } else {
        ln_from_f32(tokf + ((size_t)b * 256 + (t - 1)) * CCH, w, bb, out, lane);
    }
}

// ---------------- MFMA GEMM (bf16 A, bf16 pre-converted weights) -------------
// Y[M,N] = act(A[M,K]bf16 @ Wb[N,K]bf16^T + bias) (+Res bf16)
// Tile 128xTN (TN in {64,128}), 4 waves, BK=32. LDS rows pad 40.
// GATHER: A row m gathers 3x3 window of h2 (pool). SPLITK: blockIdx.z splits K;
// ATOMIC: fp32 atomicAdd into Yv (zero-initialized), bias added by kp==0.
template <int TN, bool GATHER, int SPLITK, bool BIAS, bool GELU_ACT, bool RES,
          bool ATOMIC>
__global__ __launch_bounds__(256) void gemm_mf(const u16* __restrict__ A,
                                               int lda,
                                               const u16* __restrict__ Bwb,
                                               const float* __restrict__ bias,
                                               const u16* __restrict__ Res,
                                               void* __restrict__ Yv, int M,
                                               int N, int K) {
    __shared__ u16 Asl[128 * 40];
    __shared__ u16 Bsl[TN * 40];
    const int tid = threadIdx.x;
    const int wave = tid >> 6, lane = tid & 63;
    const int quad = lane >> 4, l15 = lane & 15;
    const int m0 = blockIdx.y * 128, n0 = blockIdx.x * TN;
    const int kp = (SPLITK > 1) ? blockIdx.z : 0;
    const int KS = K / SPLITK;
    const int kbase = kp * KS;

    f32x4 acc[2][TN / 16];
#pragma unroll
    for (int i = 0; i < 2; i++)
#pragma unroll
        for (int j = 0; j < TN / 16; j++) acc[i][j] = (f32x4){0.f, 0.f, 0.f, 0.f};

    for (int kt = 0; kt < KS; kt += 32) {
        const int kk = kbase + kt;
#pragma unroll
        for (int L = 0; L < 2; L++) {
            int linear = L * 256 + tid;
            int row = linear >> 2, seg = linear & 3;
            int kf = kk + seg * 8;
            const u16* src;
            if (GATHER) {
                int m = m0 + row;
                int b = m >> 8, w = m & 255;
                int j = kf / 384, rem = kf - j * 384;
                int pr = 2 * (w >> 4) + j / 3 - 1;
                int pc = 2 * (w & 15) + j % 3 - 1;
                int tok = (pr >= 0 && pr < 32 && pc >= 0 && pc < 32)
                              ? (32 * pr + pc + 1)
                              : 1024;
                src = A + ((size_t)b * 1026 + tok) * 384 + rem;
            } else {
                int m = m0 + row;
                if (m >= M) m = M - 1;
                src = A + (size_t)m * lda + kf;
            }
            *(uint4*)(&Asl[row * 40 + seg * 8]) = *(const uint4*)src;
        }
#pragma unroll
        for (int L = 0; L < TN / 64; L++) {
            int linear = L * 256 + tid;
            int row = linear >> 2, seg = linear & 3;
            *(uint4*)(&Bsl[row * 40 + seg * 8]) =
                *(const uint4*)(Bwb + (size_t)(n0 + row) * K + kk + seg * 8);
        }
        __syncthreads();
        s16x8 afr[2], bfr[TN / 16];
#pragma unroll
        for (int ms = 0; ms < 2; ms++)
            afr[ms] = *(const s16x8*)(&Asl[(wave * 32 + ms * 16 + l15) * 40 +
                                           quad * 8]);
#pragma unroll
        for (int ns = 0; ns < TN / 16; ns++)
            bfr[ns] = *(const s16x8*)(&Bsl[(ns * 16 + l15) * 40 + quad * 8]);
#pragma unroll
        for (int ms = 0; ms < 2; ms++)
#pragma unroll
            for (int ns = 0; ns < TN / 16; ns++)
                acc[ms][ns] = __builtin_amdgcn_mfma_f32_16x16x32_bf16(
                    afr[ms], bfr[ns], acc[ms][ns], 0, 0, 0);
        __syncthreads();
    }
#pragma unroll
    for (int ms = 0; ms < 2; ms++) {
#pragma unroll
        for (int ns = 0; ns < TN / 16; ns++) {
            int n = n0 + ns * 16 + l15;
#pragma unroll
            for (int i = 0; i < 4; i++) {
                int m = m0 + wave * 32 + ms * 16 + quad * 4 + i;
                if (m >= M) continue;
                float v = acc[ms][ns][i];
                if (BIAS && (SPLITK == 1 || kp == 0)) v += bias[n];
                if (RES) v += b2f(Res[(size_t)m * N + n]);
                if (GELU_ACT) v = 0.5f * v * (1.f + erff(v * 0.70710678118f));
                if (ATOMIC)
                    atomicAdd((float*)Yv + (size_t)m * N + n, v);
                else
                    ((u16*)Yv)[(size_t)m * N + n] = f2b(v);
            }
        }
    }
}

// ---------------- sparse window attention, patch queries (dual) --------------
// One wave handles queries p0=2*idx and p0+1: lanes 0..31 score q0's keys,
// lanes 32..63 score q1's. Half-wave softmax. PV half-wave, 2 dims/lane.
// R16: PV trip count fixed at 26 (max nk) -> full unroll, all V-loads in
// flight before the FMA chain. j>=nk: shuffled pe==0 and tok==0 (valid CLS
// row address), so extra trips add exactly 0 in the same order -> bitwise
// identical result. 64-thread blocks are a measured optimum.
__global__ __launch_bounds__(64) void attn_patch(u16* __restrict__ qkv) {
    int bid = blockIdx.x;
    int idx = bid & 511;
    int hb = bid >> 9;
    int h = hb % 6, b = hb / 6;
    int lane = threadIdx.x;
    int hl = lane >> 5, l5 = lane & 31;
    int p0 = idx * 2;
    int p = p0 | hl;  // p0 even
    int r = p >> 5, c = p & 31;
    int rlo, rhi, clo, chi;
    if (r & 1) { rlo = (r - 2 < 0) ? 0 : r - 2; rhi = (r + 2 > 31) ? 31 : r + 2; }
    else       { rlo = (r - 1 < 0) ? 0 : r - 1; rhi = (r + 1 > 31) ? 31 : r + 1; }
    if (c & 1) { clo = (c - 2 < 0) ? 0 : c - 2; chi = (c + 2 > 31) ? 31 : c + 2; }
    else       { clo = (c - 1 < 0) ? 0 : c - 1; chi = (c + 1 > 31) ? 31 : c + 1; }
    int nr = rhi - rlo + 1, nc = chi - clo + 1;
    int nk = nr * nc + 1;  // + CLS at slot 0 (per half); nk in [5,26]
    int tok = 0;           // slot 0 = CLS (token 0); also lanes >= nk
    if (l5 >= 1 && l5 < nk) {
        int jj = l5 - 1;
        tok = 1 + ((rlo + jj / nc) << 5) + (clo + jj % nc);
    }
    u16* base = qkv + (size_t)b * 1026 * 1152 + h * 64;
    __shared__ float qsh[2][64];
    qsh[0][lane] = b2f(base[(size_t)(1 + p0) * 1152 + lane]);
    qsh[1][lane] = b2f(base[(size_t)(2 + p0) * 1152 + lane]);
    __syncthreads();
    float sc = NEG_BIG;
    if (l5 < nk) {
        const u16* krow = base + (size_t)tok * 1152 + 384;
        float acc = 0.f;
#pragma unroll
        for (int d0 = 0; d0 < 64; d0 += 8)
            acc += dot8(qsh[hl], d0, *(const uint4*)(krow + d0));
        sc = acc * SCALE;
    }
    float mx = fmaxf(half_max(sc), 0.f);  // per-half max, incl pad logit 0
    float pe = (l5 < nk) ? expf(sc - mx) : 0.f;
    float Z = half_sum(pe) + expf(-mx);  // pad key: weight exp(-mx), value 0
    // PV: each half handles its own query; lane covers dims 2*l5, 2*l5+1.
    // Fixed 26 trips (compile-time) -> unrolled, loads batched ahead of FMAs.
    float o0 = 0.f, o1 = 0.f;
#pragma unroll
    for (int j = 0; j < 26; j++) {
        int t = __shfl(tok, (hl << 5) | j, 64);
        float wj = __shfl(pe, (hl << 5) | j, 64);
        u32 vv = *(const u32*)(base + (size_t)t * 1152 + 768 + 2 * l5);
        o0 += wj * b2f((u16)vv);
        o1 += wj * b2f((u16)(vv >> 16));
    }
    float zi = 1.f / Z;
    u32 packed = (u32)f2b(o0 * zi) | ((u32)f2b(o1 * zi) << 16);
    *(u32*)(base + (size_t)(1 + p) * 1152 + 2 * l5) = packed;
}

// ---------------- dense attention for CLS query (row 0) ----------------------
// 16 waves: per-thread key dots; block softmax; PV by (wave=key%16, lane=dim).
__global__ __launch_bounds__(1024) void attn_cls(u16* __restrict__ qkv) {
    int h = blockIdx.x % 6, b = blockIdx.x / 6;
    u16* base = qkv + (size_t)b * 1026 * 1152 + h * 64;
    int tid = threadIdx.x, lane = tid & 63, wv = tid >> 6;  // wv 0..15
    __shared__ float sc[1026];
    __shared__ float qsh[64];
    __shared__ float redmax[16], redsum[16];
    __shared__ float pv[16][64];
    if (tid < 64) qsh[tid] = b2f(base[tid]);
    __syncthreads();
    for (int key = tid; key < 1026; key += 1024) {
        const u16* krow = base + (size_t)key * 1152 + 384;
        float acc = 0.f;
#pragma unroll
        for (int d0 = 0; d0 < 64; d0 += 8)
            acc += dot8(qsh, d0, *(const uint4*)(krow + d0));
        sc[key] = acc * SCALE;
    }
    __syncthreads();
    float lm = NEG_BIG;
    for (int key = tid; key < 1026; key += 1024) lm = fmaxf(lm, sc[key]);
    lm = wave_max(lm);
    if (lane == 0) redmax[wv] = lm;
    __syncthreads();
    float mx = NEG_BIG;
#pragma unroll
    for (int i = 0; i < 16; i++) mx = fmaxf(mx, redmax[i]);
    float lsum = 0.f;
    for (int key = tid; key < 1026; key += 1024) {
        float e = expf(sc[key] - mx);
        sc[key] = e;
        lsum += e;
    }
    lsum = wave_sum(lsum);
    if (lane == 0) redsum[wv] = lsum;
    __syncthreads();
    float Z = 0.f;
#pragma unroll
    for (int i = 0; i < 16; i++) Z += redsum[i];
    float acc = 0.f;
    for (int key = wv; key < 1026; key += 16)
        acc += sc[key] * b2f(base[(size_t)key * 1152 + 768 + lane]);
    pv[wv][lane] = acc;
    __syncthreads();
    if (tid < 64) {
        float s = 0.f;
#pragma unroll
        for (int w2 = 0; w2 < 16; w2++) s += pv[w2][tid];
        base[tid] = f2b(s / Z);
        base[(size_t)1025 * 1152 + tid] = 0;  // att pad row (q-cols)
    }
}

extern "C" void kernel_launch(void* const* d_in, const int* in_sizes, int n_in,
                              void* d_out, int out_size, void* d_ws,
                              size_t ws_size, hipStream_t stream) {
    const float* x      = (const float*)d_in[0];
    const float* n1w    = (const float*)d_in[1];
    const float* n1b    = (const float*)d_in[2];
    const float* qkv_w  = (const float*)d_in[3];
    const float* proj_w = (const float*)d_in[4];
    const float* proj_b = (const float*)d_in[5];
    const float* n2w    = (const float*)d_in[6];
    const float* n2b    = (const float*)d_in[7];
    const float* pool_w = (const float*)d_in[8];
    const float* pool_b = (const float*)d_in[9];
    const float* n3w    = (const float*)d_in[10];
    const float* n3b    = (const float*)d_in[11];
    const float* fc1_w  = (const float*)d_in[12];
    const float* fc1_b  = (const float*)d_in[13];
    const float* fc2_w  = (const float*)d_in[14];
    const float* fc2_b  = (const float*)d_in[15];

    u16* ws = (u16*)d_ws;
    u16* h1    = ws;                      // 8208*384
    u16* qkvb  = ws + 3151872;            // 8208*1152
    u16* wb    = ws + 12607488;           // 3,096,576 bf16 weights
    float* tokf = (float*)qkvb;           // 2048*384 fp32 (reuse after proj)
    u16* h3    = qkvb + 1572864;          // 2056*384
    u16* mlp1  = qkvb + 2362368;          // 2056*1536

    // 0. prologue: LN1 || weight cvt || zero d_out (split-K accumulator)
    prologue<<<PRO_LN + PRO_CVT + PRO_ZERO, 256, 0, stream>>>(
        x, n1w, n1b, h1, qkv_w, proj_w, pool_w, fc1_w, fc2_w, wb,
        (float*)d_out);
    // 1. qkv = h1 @ qkv_w^T  (8208 x 1152 x 384), 128x128 tile
    gemm_mf<128, false, 1, false, false, false, false>
        <<<dim3(1152 / 128, 65), 256, 0, stream>>>(h1, 384, wb + W_QKV,
                                                   nullptr, nullptr, qkvb,
                                                   8208, 1152, 384);
    // 2. sparse attention -> att into q-columns of qkvb
    attn_patch<<<8 * 6 * 512, 64, 0, stream>>>(qkvb);
    attn_cls<<<8 * 6, 1024, 0, stream>>>(qkvb);
    // 3. h1 = h1 + att @ proj_w^T + proj_b  (A = qkvb q-cols, lda=1152)
    gemm_mf<64, false, 1, true, false, true, false>
        <<<dim3(384 / 64, 65), 256, 0, stream>>>(qkvb, 1152, wb + W_PROJ,
                                                 proj_b, h1, h1, 8208, 384,
                                                 384);
    // 4. midk: LN2 in-place || zero tokf (aliases qkvb — dead after proj)
    midk<<<MID_LN + MID_ZERO, 256, 0, stream>>>(h1, n2w, n2b, tokf);
    // 5. tokf += gather(h1) @ pool_w^T (+ pool_b on kp==0)  split-K=4
    gemm_mf<64, true, 4, true, false, false, true>
        <<<dim3(384 / 64, 16, 4), 256, 0, stream>>>(h1, 384, wb + W_POOL,
                                                    pool_b, nullptr, tokf,
                                                    2048, 384, 3456);
    // 6. h3 = LN3(concat(h1[:,0], tokf))
    ln3_concat<<<8 * 257, 64, 0, stream>>>(h1, tokf, n3w, n3b, h3);
    // 7. mlp1 = gelu(h3 @ fc1_w^T + fc1_b)  (2056 x 1536 x 384)
    gemm_mf<64, false, 1, true, true, false, false>
        <<<dim3(1536 / 64, 17), 256, 0, stream>>>(h3, 384, wb + W_FC1, fc1_b,
                                                  nullptr, mlp1, 2056, 1536,
                                                  384);
    // 8. d_out += mlp1 @ fc2_w^T (+ fc2_b on kp==0)  split-K=4, fp32 out
    gemm_mf<64, false, 4, true, false, false, true>
        <<<dim3(384 / 64, 17, 4), 256, 0, stream>>>(mlp1, 1536, wb + W_FC2,
                                                    fc2_b, nullptr, d_out,
                                                    2056, 384, 1536);
}

// Round 17
// 273.329 us; speedup vs baseline: 1.1381x; 1.0045x over previous
//
#include <hip/hip_runtime.h>

// ConvAttention forward, MI355X. fp32 I/O, bf16 intermediates, MFMA GEMMs.
// Round-16 proven structure (274.5 us) + R17: attn_cls PV loop fixed at 65
// trips (compile-time unroll -> V-loads batched ahead of the FMA chain;
// key>=1026 trips have p=0 and clamped valid address -> exact no-ops).
// R16 (validated +10us): attn_patch PV fixed at 26 trips, same technique.
//   prologue = LN1 || cvt_weights(fp32->bf16) || zero(d_out)
//   qkv GEMM (128x128 tile) -> attn_patch (dual-query, half-wave PV)
//   -> attn_cls (16 waves) -> proj GEMM (+residual) -> midk (LN2 || zero tokf)
//   -> pool GEMM (fused 3x3 gather, split-K=4, atomic) -> ln3 -> fc1 -> fc2.
// GEMM: 128xTN tile, 4 waves, BK=32, LDS row pitch 40 (conflict-free b128).
// Negative results worth keeping (measured): BK=64 regressed (-18 us,
// occupancy loss > barrier savings); grouping attention waves into 256/1024-
// thread blocks regressed 1.7x (barrier tail-gating + L1 thrash).
// ws (u16 units): h1 [0, 3151872) ; qkvb [3151872, 12607488) ;
//   wb [12607488, 15704064)  (bf16 weights: qkv|proj|pool|fc1|fc2)
//   att = q-cols of qkvb (lda 1152). After proj, qkvb region reused:
//   tokf (fp32) at qkvb+0 ; h3 at qkvb+1572864 ; mlp1 at qkvb+2362368.
// NOTE: tokf zeroing rides midk, stream-ordered AFTER proj (qkvb alias).

typedef unsigned short u16;
typedef unsigned int u32;
typedef short s16x8 __attribute__((ext_vector_type(8)));
typedef float f32x4 __attribute__((ext_vector_type(4)));

__device__ __forceinline__ float b2f(u16 u) {
    return __uint_as_float(((u32)u) << 16);
}
__device__ __forceinline__ u16 f2b(float f) {
    u32 u = __float_as_uint(f);
    return (u16)((u + 0x7FFFu + ((u >> 16) & 1u)) >> 16);  // RTNE
}
__device__ __forceinline__ float wave_sum(float v) {
#pragma unroll
    for (int o = 32; o > 0; o >>= 1) v += __shfl_xor(v, o, 64);
    return v;
}
__device__ __forceinline__ float wave_max(float v) {
#pragma unroll
    for (int o = 32; o > 0; o >>= 1) v = fmaxf(v, __shfl_xor(v, o, 64));
    return v;
}
__device__ __forceinline__ float half_sum(float v) {
#pragma unroll
    for (int o = 16; o > 0; o >>= 1) v += __shfl_xor(v, o, 64);
    return v;
}
__device__ __forceinline__ float half_max(float v) {
#pragma unroll
    for (int o = 16; o > 0; o >>= 1) v = fmaxf(v, __shfl_xor(v, o, 64));
    return v;
}
__device__ __forceinline__ float dot8(const float* qsh, int d0, uint4 u) {
    return qsh[d0 + 0] * b2f((u16)(u.x)) + qsh[d0 + 1] * b2f((u16)(u.x >> 16)) +
           qsh[d0 + 2] * b2f((u16)(u.y)) + qsh[d0 + 3] * b2f((u16)(u.y >> 16)) +
           qsh[d0 + 4] * b2f((u16)(u.z)) + qsh[d0 + 5] * b2f((u16)(u.z >> 16)) +
           qsh[d0 + 6] * b2f((u16)(u.w)) + qsh[d0 + 7] * b2f((u16)(u.w >> 16));
}

#define CCH 384
#define SCALE 0.40824829046386302f  // H^-0.5 = 6^-0.5
#define NEG_BIG (-1e30f)

// weight segment offsets in wb (u16 units)
#define W_QKV 0
#define W_PROJ 442368
#define W_POOL 589824
#define W_FC1 1916928
#define W_FC2 2506752
#define W_TOTAL 3096576

// ---------------- LN row helpers (per-wave, no block barriers) ---------------
__device__ __forceinline__ void ln_from_f32(const float* in, const float* w,
                                            const float* bb, u16* out,
                                            int lane) {
    float v[6];
    float s = 0.f, ss = 0.f;
#pragma unroll
    for (int i = 0; i < 6; i++) {
        v[i] = in[lane + 64 * i];
        s += v[i];
        ss += v[i] * v[i];
    }
    s = wave_sum(s);
    ss = wave_sum(ss);
    float mu = s * (1.f / 384.f);
    float var = ss * (1.f / 384.f) - mu * mu;
    float inv = rsqrtf(var + 1e-5f);
#pragma unroll
    for (int i = 0; i < 6; i++) {
        int c = lane + 64 * i;
        out[c] = f2b((v[i] - mu) * inv * w[c] + bb[c]);
    }
}
__device__ __forceinline__ void ln_from_b16(const u16* in, const float* w,
                                            const float* bb, u16* out,
                                            int lane) {
    float v[6];
    float s = 0.f, ss = 0.f;
#pragma unroll
    for (int i = 0; i < 6; i++) {
        v[i] = b2f(in[lane + 64 * i]);
        s += v[i];
        ss += v[i] * v[i];
    }
    s = wave_sum(s);
    ss = wave_sum(ss);
    float mu = s * (1.f / 384.f);
    float var = ss * (1.f / 384.f) - mu * mu;
    float inv = rsqrtf(var + 1e-5f);
#pragma unroll
    for (int i = 0; i < 6; i++) {
        int c = lane + 64 * i;
        out[c] = f2b((v[i] - mu) * inv * w[c] + bb[c]);
    }
}

// ---------------- prologue: LN1 || cvt_weights || zero(d_out) ----------------
#define PRO_LN 2052
#define PRO_CVT 1512
#define PRO_ZERO 771
__global__ __launch_bounds__(256) void prologue(
    const float* __restrict__ x, const float* __restrict__ n1w,
    const float* __restrict__ n1b, u16* __restrict__ h1,
    const float* __restrict__ qkv_w, const float* __restrict__ proj_w,
    const float* __restrict__ pool_w, const float* __restrict__ fc1_w,
    const float* __restrict__ fc2_w, u16* __restrict__ wb,
    float* __restrict__ dout) {
    int bid = blockIdx.x, tid = threadIdx.x;
    if (bid < PRO_LN) {
        int wv = tid >> 6, lane = tid & 63;
        int row = bid * 4 + wv;  // < 8208
        int t = row % 1026, b = row / 1026;
        u16* out = h1 + (size_t)row * CCH;
        if (t == 1025) {
#pragma unroll
            for (int i = 0; i < 6; i++) out[lane + 64 * i] = 0;
            return;
        }
        ln_from_f32(x + ((size_t)b * 1025 + t) * CCH, n1w, n1b, out, lane);
    } else if (bid < PRO_LN + PRO_CVT) {
        size_t off = ((size_t)(bid - PRO_LN) * 256 + tid) * 8;
        if (off >= W_TOTAL) return;
        const float* src;
        size_t base;
        if (off < W_PROJ)       { src = qkv_w;  base = W_QKV; }
        else if (off < W_POOL)  { src = proj_w; base = W_PROJ; }
        else if (off < W_FC1)   { src = pool_w; base = W_POOL; }
        else if (off < W_FC2)   { src = fc1_w;  base = W_FC1; }
        else                    { src = fc2_w;  base = W_FC2; }
        size_t rel = off - base;
        float4 a = *(const float4*)(src + rel);
        float4 b = *(const float4*)(src + rel + 4);
        uint4 o;
        o.x = (u32)f2b(a.x) | ((u32)f2b(a.y) << 16);
        o.y = (u32)f2b(a.z) | ((u32)f2b(a.w) << 16);
        o.z = (u32)f2b(b.x) | ((u32)f2b(b.y) << 16);
        o.w = (u32)f2b(b.z) | ((u32)f2b(b.w) << 16);
        *(uint4*)(wb + off) = o;
    } else {
        size_t idx = ((size_t)(bid - PRO_LN - PRO_CVT) * 256 + tid) * 4;
        *(float4*)(dout + idx) = make_float4(0.f, 0.f, 0.f, 0.f);
    }
}

// ---------------- midk: LN2 (in-place) || zero(tokf) -------------------------
#define MID_LN 2050
#define MID_ZERO 768
__global__ __launch_bounds__(256) void midk(u16* __restrict__ h,
                                            const float* __restrict__ n2w,
                                            const float* __restrict__ n2b,
                                            float* __restrict__ tokf) {
    int bid = blockIdx.x, tid = threadIdx.x;
    if (bid < MID_LN) {
        int wv = tid >> 6, lane = tid & 63;
        int row = bid * 4 + wv;  // < 8200
        int b = row / 1025, t = row % 1025;
        u16* p = h + ((size_t)b * 1026 + t) * CCH;
        ln_from_b16(p, n2w, n2b, p, lane);
    } else {
        size_t idx = ((size_t)(bid - MID_LN) * 256 + tid) * 4;
        *(float4*)(tokf + idx) = make_float4(0.f, 0.f, 0.f, 0.f);
    }
}

// h3 = LN3(concat(h2[:,0] (bf16), tokf (fp32, pool bias included)))
__global__ __launch_bounds__(64) void ln3_concat(const u16* __restrict__ h2,
                                                 const float* __restrict__ tokf,
                                                 const float* __restrict__ w,
                                                 const float* __restrict__ bb,
                                                 u16* __restrict__ h3) {
    int row = blockIdx.x;  // b*257 + t
    int b = row / 257, t = row % 257;
    int lane = threadIdx.x;
    u16* out = h3 + (size_t)row * CCH;
    if (t == 0) {
        ln_from_b16(h2 + (size_t)b * 1026 * CCH, w, bb, out, lane);
    } else {
        ln_from_f32(tokf + ((size_t)b * 256 + (t - 1)) * CCH, w, bb, out, lane);
    }
}

// ---------------- MFMA GEMM (bf16 A, bf16 pre-converted weights) -------------
// Y[M,N] = act(A[M,K]bf16 @ Wb[N,K]bf16^T + bias) (+Res bf16)
// Tile 128xTN (TN in {64,128}), 4 waves, BK=32. LDS rows pad 40.
// GATHER: A row m gathers 3x3 window of h2 (pool). SPLITK: blockIdx.z splits K;
// ATOMIC: fp32 atomicAdd into Yv (zero-initialized), bias added by kp==0.
template <int TN, bool GATHER, int SPLITK, bool BIAS, bool GELU_ACT, bool RES,
          bool ATOMIC>
__global__ __launch_bounds__(256) void gemm_mf(const u16* __restrict__ A,
                                               int lda,
                                               const u16* __restrict__ Bwb,
                                               const float* __restrict__ bias,
                                               const u16* __restrict__ Res,
                                               void* __restrict__ Yv, int M,
                                               int N, int K) {
    __shared__ u16 Asl[128 * 40];
    __shared__ u16 Bsl[TN * 40];
    const int tid = threadIdx.x;
    const int wave = tid >> 6, lane = tid & 63;
    const int quad = lane >> 4, l15 = lane & 15;
    const int m0 = blockIdx.y * 128, n0 = blockIdx.x * TN;
    const int kp = (SPLITK > 1) ? blockIdx.z : 0;
    const int KS = K / SPLITK;
    const int kbase = kp * KS;

    f32x4 acc[2][TN / 16];
#pragma unroll
    for (int i = 0; i < 2; i++)
#pragma unroll
        for (int j = 0; j < TN / 16; j++) acc[i][j] = (f32x4){0.f, 0.f, 0.f, 0.f};

    for (int kt = 0; kt < KS; kt += 32) {
        const int kk = kbase + kt;
#pragma unroll
        for (int L = 0; L < 2; L++) {
            int linear = L * 256 + tid;
            int row = linear >> 2, seg = linear & 3;
            int kf = kk + seg * 8;
            const u16* src;
            if (GATHER) {
                int m = m0 + row;
                int b = m >> 8, w = m & 255;
                int j = kf / 384, rem = kf - j * 384;
                int pr = 2 * (w >> 4) + j / 3 - 1;
                int pc = 2 * (w & 15) + j % 3 - 1;
                int tok = (pr >= 0 && pr < 32 && pc >= 0 && pc < 32)
                              ? (32 * pr + pc + 1)
                              : 1024;
                src = A + ((size_t)b * 1026 + tok) * 384 + rem;
            } else {
                int m = m0 + row;
                if (m >= M) m = M - 1;
                src = A + (size_t)m * lda + kf;
            }
            *(uint4*)(&Asl[row * 40 + seg * 8]) = *(const uint4*)src;
        }
#pragma unroll
        for (int L = 0; L < TN / 64; L++) {
            int linear = L * 256 + tid;
            int row = linear >> 2, seg = linear & 3;
            *(uint4*)(&Bsl[row * 40 + seg * 8]) =
                *(const uint4*)(Bwb + (size_t)(n0 + row) * K + kk + seg * 8);
        }
        __syncthreads();
        s16x8 afr[2], bfr[TN / 16];
#pragma unroll
        for (int ms = 0; ms < 2; ms++)
            afr[ms] = *(const s16x8*)(&Asl[(wave * 32 + ms * 16 + l15) * 40 +
                                           quad * 8]);
#pragma unroll
        for (int ns = 0; ns < TN / 16; ns++)
            bfr[ns] = *(const s16x8*)(&Bsl[(ns * 16 + l15) * 40 + quad * 8]);
#pragma unroll
        for (int ms = 0; ms < 2; ms++)
#pragma unroll
            for (int ns = 0; ns < TN / 16; ns++)
                acc[ms][ns] = __builtin_amdgcn_mfma_f32_16x16x32_bf16(
                    afr[ms], bfr[ns], acc[ms][ns], 0, 0, 0);
        __syncthreads();
    }
#pragma unroll
    for (int ms = 0; ms < 2; ms++) {
#pragma unroll
        for (int ns = 0; ns < TN / 16; ns++) {
            int n = n0 + ns * 16 + l15;
#pragma unroll
            for (int i = 0; i < 4; i++) {
                int m = m0 + wave * 32 + ms * 16 + quad * 4 + i;
                if (m >= M) continue;
                float v = acc[ms][ns][i];
                if (BIAS && (SPLITK == 1 || kp == 0)) v += bias[n];
                if (RES) v += b2f(Res[(size_t)m * N + n]);
                if (GELU_ACT) v = 0.5f * v * (1.f + erff(v * 0.70710678118f));
                if (ATOMIC)
                    atomicAdd((float*)Yv + (size_t)m * N + n, v);
                else
                    ((u16*)Yv)[(size_t)m * N + n] = f2b(v);
            }
        }
    }
}

// ---------------- sparse window attention, patch queries (dual) --------------
// One wave handles queries p0=2*idx and p0+1: lanes 0..31 score q0's keys,
// lanes 32..63 score q1's. Half-wave softmax. PV half-wave, 2 dims/lane.
// PV trip count fixed at 26 (max nk) -> full unroll, all V-loads in flight
// before the FMA chain (R16, validated +10us). j>=nk: shuffled pe==0 and
// tok==0 (valid CLS row), so extra trips are exact no-ops.
__global__ __launch_bounds__(64) void attn_patch(u16* __restrict__ qkv) {
    int bid = blockIdx.x;
    int idx = bid & 511;
    int hb = bid >> 9;
    int h = hb % 6, b = hb / 6;
    int lane = threadIdx.x;
    int hl = lane >> 5, l5 = lane & 31;
    int p0 = idx * 2;
    int p = p0 | hl;  // p0 even
    int r = p >> 5, c = p & 31;
    int rlo, rhi, clo, chi;
    if (r & 1) { rlo = (r - 2 < 0) ? 0 : r - 2; rhi = (r + 2 > 31) ? 31 : r + 2; }
    else       { rlo = (r - 1 < 0) ? 0 : r - 1; rhi = (r + 1 > 31) ? 31 : r + 1; }
    if (c & 1) { clo = (c - 2 < 0) ? 0 : c - 2; chi = (c + 2 > 31) ? 31 : c + 2; }
    else       { clo = (c - 1 < 0) ? 0 : c - 1; chi = (c + 1 > 31) ? 31 : c + 1; }
    int nr = rhi - rlo + 1, nc = chi - clo + 1;
    int nk = nr * nc + 1;  // + CLS at slot 0 (per half); nk in [5,26]
    int tok = 0;           // slot 0 = CLS (token 0); also lanes >= nk
    if (l5 >= 1 && l5 < nk) {
        int jj = l5 - 1;
        tok = 1 + ((rlo + jj / nc) << 5) + (clo + jj % nc);
    }
    u16* base = qkv + (size_t)b * 1026 * 1152 + h * 64;
    __shared__ float qsh[2][64];
    qsh[0][lane] = b2f(base[(size_t)(1 + p0) * 1152 + lane]);
    qsh[1][lane] = b2f(base[(size_t)(2 + p0) * 1152 + lane]);
    __syncthreads();
    float sc = NEG_BIG;
    if (l5 < nk) {
        const u16* krow = base + (size_t)tok * 1152 + 384;
        float acc = 0.f;
#pragma unroll
        for (int d0 = 0; d0 < 64; d0 += 8)
            acc += dot8(qsh[hl], d0, *(const uint4*)(krow + d0));
        sc = acc * SCALE;
    }
    float mx = fmaxf(half_max(sc), 0.f);  // per-half max, incl pad logit 0
    float pe = (l5 < nk) ? expf(sc - mx) : 0.f;
    float Z = half_sum(pe) + expf(-mx);  // pad key: weight exp(-mx), value 0
    // PV: each half handles its own query; lane covers dims 2*l5, 2*l5+1.
    float o0 = 0.f, o1 = 0.f;
#pragma unroll
    for (int j = 0; j < 26; j++) {
        int t = __shfl(tok, (hl << 5) | j, 64);
        float wj = __shfl(pe, (hl << 5) | j, 64);
        u32 vv = *(const u32*)(base + (size_t)t * 1152 + 768 + 2 * l5);
        o0 += wj * b2f((u16)vv);
        o1 += wj * b2f((u16)(vv >> 16));
    }
    float zi = 1.f / Z;
    u32 packed = (u32)f2b(o0 * zi) | ((u32)f2b(o1 * zi) << 16);
    *(u32*)(base + (size_t)(1 + p) * 1152 + 2 * l5) = packed;
}

// ---------------- dense attention for CLS query (row 0) ----------------------
// 16 waves: per-thread key dots; block softmax; PV by (wave=key%16, lane=dim).
// R17: PV trip count fixed at 65 (compile-time) with predicated weight and
// address clamped to row 1025 (valid pad row) -> loads batched ahead of FMAs;
// key>=1026 trips contribute exactly 0 in the same order (bitwise identical).
__global__ __launch_bounds__(1024) void attn_cls(u16* __restrict__ qkv) {
    int h = blockIdx.x % 6, b = blockIdx.x / 6;
    u16* base = qkv + (size_t)b * 1026 * 1152 + h * 64;
    int tid = threadIdx.x, lane = tid & 63, wv = tid >> 6;  // wv 0..15
    __shared__ float sc[1026];
    __shared__ float qsh[64];
    __shared__ float redmax[16], redsum[16];
    __shared__ float pv[16][64];
    if (tid < 64) qsh[tid] = b2f(base[tid]);
    __syncthreads();
    for (int key = tid; key < 1026; key += 1024) {
        const u16* krow = base + (size_t)key * 1152 + 384;
        float acc = 0.f;
#pragma unroll
        for (int d0 = 0; d0 < 64; d0 += 8)
            acc += dot8(qsh, d0, *(const uint4*)(krow + d0));
        sc[key] = acc * SCALE;
    }
    __syncthreads();
    float lm = NEG_BIG;
    for (int key = tid; key < 1026; key += 1024) lm = fmaxf(lm, sc[key]);
    lm = wave_max(lm);
    if (lane == 0) redmax[wv] = lm;
    __syncthreads();
    float mx = NEG_BIG;
#pragma unroll
    for (int i = 0; i < 16; i++) mx = fmaxf(mx, redmax[i]);
    float lsum = 0.f;
    for (int key = tid; key < 1026; key += 1024) {
        float e = expf(sc[key] - mx);
        sc[key] = e;
        lsum += e;
    }
    lsum = wave_sum(lsum);
    if (lane == 0) redsum[wv] = lsum;
    __syncthreads();
    float Z = 0.f;
#pragma unroll
    for (int i = 0; i < 16; i++) Z += redsum[i];
    // PV: wave wv covers keys wv, wv+16, ... — fixed 65 trips, predicated.
    float acc = 0.f;
#pragma unroll
    for (int t = 0; t < 65; t++) {
        int key = wv + 16 * t;
        bool ok = key < 1026;
        int kc = ok ? key : 1025;  // row 1025 = zero pad row (valid address)
        float p = ok ? sc[kc] : 0.f;
        acc += p * b2f(base[(size_t)kc * 1152 + 768 + lane]);
    }
    pv[wv][lane] = acc;
    __syncthreads();
    if (tid < 64) {
        float s = 0.f;
#pragma unroll
        for (int w2 = 0; w2 < 16; w2++) s += pv[w2][tid];
        base[tid] = f2b(s / Z);
        base[(size_t)1025 * 1152 + tid] = 0;  // att pad row (q-cols)
    }
}

extern "C" void kernel_launch(void* const* d_in, const int* in_sizes, int n_in,
                              void* d_out, int out_size, void* d_ws,
                              size_t ws_size, hipStream_t stream) {
    const float* x      = (const float*)d_in[0];
    const float* n1w    = (const float*)d_in[1];
    const float* n1b    = (const float*)d_in[2];
    const float* qkv_w  = (const float*)d_in[3];
    const float* proj_w = (const float*)d_in[4];
    const float* proj_b = (const float*)d_in[5];
    const float* n2w    = (const float*)d_in[6];
    const float* n2b    = (const float*)d_in[7];
    const float* pool_w = (const float*)d_in[8];
    const float* pool_b = (const float*)d_in[9];
    const float* n3w    = (const float*)d_in[10];
    const float* n3b    = (const float*)d_in[11];
    const float* fc1_w  = (const float*)d_in[12];
    const float* fc1_b  = (const float*)d_in[13];
    const float* fc2_w  = (const float*)d_in[14];
    const float* fc2_b  = (const float*)d_in[15];

    u16* ws = (u16*)d_ws;
    u16* h1    = ws;                      // 8208*384
    u16* qkvb  = ws + 3151872;            // 8208*1152
    u16* wb    = ws + 12607488;           // 3,096,576 bf16 weights
    float* tokf = (float*)qkvb;           // 2048*384 fp32 (reuse after proj)
    u16* h3    = qkvb + 1572864;          // 2056*384
    u16* mlp1  = qkvb + 2362368;          // 2056*1536

    // 0. prologue: LN1 || weight cvt || zero d_out (split-K accumulator)
    prologue<<<PRO_LN + PRO_CVT + PRO_ZERO, 256, 0, stream>>>(
        x, n1w, n1b, h1, qkv_w, proj_w, pool_w, fc1_w, fc2_w, wb,
        (float*)d_out);
    // 1. qkv = h1 @ qkv_w^T  (8208 x 1152 x 384), 128x128 tile
    gemm_mf<128, false, 1, false, false, false, false>
        <<<dim3(1152 / 128, 65), 256, 0, stream>>>(h1, 384, wb + W_QKV,
                                                   nullptr, nullptr, qkvb,
                                                   8208, 1152, 384);
    // 2. sparse attention -> att into q-columns of qkvb
    attn_patch<<<8 * 6 * 512, 64, 0, stream>>>(qkvb);
    attn_cls<<<8 * 6, 1024, 0, stream>>>(qkvb);
    // 3. h1 = h1 + att @ proj_w^T + proj_b  (A = qkvb q-cols, lda=1152)
    gemm_mf<64, false, 1, true, false, true, false>
        <<<dim3(384 / 64, 65), 256, 0, stream>>>(qkvb, 1152, wb + W_PROJ,
                                                 proj_b, h1, h1, 8208, 384,
                                                 384);
    // 4. midk: LN2 in-place || zero tokf (aliases qkvb — dead after proj)
    midk<<<MID_LN + MID_ZERO, 256, 0, stream>>>(h1, n2w, n2b, tokf);
    // 5. tokf += gather(h1) @ pool_w^T (+ pool_b on kp==0)  split-K=4
    gemm_mf<64, true, 4, true, false, false, true>
        <<<dim3(384 / 64, 16, 4), 256, 0, stream>>>(h1, 384, wb + W_POOL,
                                                    pool_b, nullptr, tokf,
                                                    2048, 384, 3456);
    // 6. h3 = LN3(concat(h1[:,0], tokf))
    ln3_concat<<<8 * 257, 64, 0, stream>>>(h1, tokf, n3w, n3b, h3);
    // 7. mlp1 = gelu(h3 @ fc1_w^T + fc1_b)  (2056 x 1536 x 384)
    gemm_mf<64, false, 1, true, true, false, false>
        <<<dim3(1536 / 64, 17), 256, 0, stream>>>(h3, 384, wb + W_FC1, fc1_b,
                                                  nullptr, mlp1, 2056, 1536,
                                                  384);
    // 8. d_out += mlp1 @ fc2_w^T (+ fc2_b on kp==0)  split-K=4, fp32 out
    gemm_mf<64, false, 4, true, false, false, true>
        <<<dim3(384 / 64, 17, 4), 256, 0, stream>>>(mlp1, 1536, wb + W_FC2,
                                                    fc2_b, nullptr, d_out,
                                                    2056, 384, 1536);
}